// Round 16
// baseline (321.386 us; speedup 1.0000x reference)
//
#include <hip/hip_runtime.h>
#include <stdint.h>

#define BATCH 4
#define CINCH 3
#define HIN 128
#define WIN 128
#define NN 4096      // 64*64 output nodes per batch
#define CF 64        // feature channels
#define KNN 7

typedef unsigned short u16;
typedef unsigned u32;
typedef unsigned long long u64;
typedef __attribute__((ext_vector_type(8))) short bf16x8;
typedef __attribute__((ext_vector_type(4))) float f32x4;

// ---------------------------------------------------------------- helpers
__device__ __forceinline__ u64 u64min(u64 a, u64 b) { return a < b ? a : b; }
__device__ __forceinline__ u32 u32min(u32 a, u32 b) { return a < b ? a : b; }

__device__ __forceinline__ u32 med3_u32(u32 a, u32 b, u32 c) {
    u32 d;
    asm("v_med3_u32 %0, %1, %2, %3" : "=v"(d) : "v"(a), "v"(b), "v"(c));
    return d;
}

// branchless sorted top-8 insert (ascending)
__device__ __forceinline__ void insert8_med3(u32* l, u32 k) {
    l[7] = med3_u32(l[6], l[7], k);
    l[6] = med3_u32(l[5], l[6], k);
    l[5] = med3_u32(l[4], l[5], k);
    l[4] = med3_u32(l[3], l[4], k);
    l[3] = med3_u32(l[2], l[3], k);
    l[2] = med3_u32(l[1], l[2], k);
    l[1] = med3_u32(l[0], l[1], k);
    l[0] = u32min(l[0], k);
}

template <int M>
__device__ __forceinline__ void insertM64(u64* lst, u64 k) {
    u64 cur = k;
#pragma unroll
    for (int i = 0; i < M; ++i) {
        u64 lo = u64min(lst[i], cur);
        u64 hi = (lst[i] < cur) ? cur : lst[i];
        lst[i] = lo;
        cur = hi;
    }
}

// ------------------------------------------------ K1: conv + sq + quant + adj zeros
// EXACT copy of the R14 kernel (138.6 µs round).
__global__ __launch_bounds__(256) void conv_fused_kernel(
    const float* __restrict__ x, const float* __restrict__ w,
    const float* __restrict__ bias, float* __restrict__ y,
    u16* __restrict__ ybf, float* __restrict__ sq, float4* __restrict__ adj4) {
    __shared__ float ws[CF * CINCH * 9];
    __shared__ float bs[CF];
    for (int i = threadIdx.x; i < CF * CINCH * 9; i += 256) ws[i] = w[i];
    if (threadIdx.x < CF) bs[threadIdx.x] = bias[threadIdx.x];

    {
        float4* dst = adj4 + (size_t)blockIdx.x * 4096;
        const float4 z = make_float4(0.f, 0.f, 0.f, 0.f);
#pragma unroll
        for (int k = 0; k < 16; ++k) dst[k * 256 + threadIdx.x] = z;
    }
    __syncthreads();

    int gid = blockIdx.x * 256 + threadIdx.x;   // ((b*4096)+n)*64 + c
    int c = gid & 63;                            // == lane
    int n = (gid >> 6) & (NN - 1);
    int b = gid >> 18;
    int oh = n >> 6, ow = n & 63;
    const float* xb = x + (size_t)b * CINCH * HIN * WIN;
    float acc = bs[c];
#pragma unroll
    for (int cin = 0; cin < CINCH; ++cin) {
#pragma unroll
        for (int kh = 0; kh < 3; ++kh) {
            int ih = oh * 2 - 1 + kh;
            if (ih < 0 || ih >= HIN) continue;
#pragma unroll
            for (int kw = 0; kw < 3; ++kw) {
                int iw = ow * 2 - 1 + kw;
                if (iw < 0 || iw >= WIN) continue;
                acc += xb[(cin * HIN + ih) * WIN + iw] *
                       ws[(c * CINCH + cin) * 9 + kh * 3 + kw];
            }
        }
    }
    y[(size_t)gid] = acc;

    uint32_t u = __float_as_uint(acc);
    ybf[(size_t)gid] = (u16)((u + 0x7fffu + ((u >> 16) & 1u)) >> 16);

    float s = acc * acc;
#pragma unroll
    for (int off = 32; off; off >>= 1) s += __shfl_xor(s, off, 64);
    if (c == 0) sq[gid >> 6] = s;
}

// ------------------------------------------------ K2: screen + rescore + ones
// EXACT copy of the R14 kernel. Idempotent: re-running it rewrites identical
// ones over adj; all other state is block-local.
__global__ __launch_bounds__(256, 4) void screen_kernel(
    const u16* __restrict__ ybf, const float* __restrict__ yf,
    const float* __restrict__ sq, float* __restrict__ adj) {
    __shared__ float sqlds[NN];          // 16 KB
    __shared__ u32 mlds[16 * 129];       // 8.25 KB
    __shared__ u64 ckey[16][32];         // 4 KB
    __shared__ u32 cidx[16][32];         // 2 KB

    const int bid = blockIdx.x;
    const int b = bid >> 8;
    const int r0 = (bid & 255) << 4;     // 16 rows per block
    const int tid = threadIdx.x, w = tid >> 6, lane = tid & 63;
    const int lc = lane & 15, g = lane >> 4;
    const size_t nb = (size_t)b * NN;

    {
        const float4* s4 = (const float4*)(sq + nb);
        float4* d4 = (float4*)sqlds;
#pragma unroll
        for (int i = 0; i < 4; ++i) d4[i * 256 + tid] = s4[i * 256 + tid];
    }

    const int row = r0 + lc;
    bf16x8 rf0 = *(const bf16x8*)(ybf + (nb + row) * CF + g * 8);
    bf16x8 rf1 = *(const bf16x8*)(ybf + (nb + row) * CF + 32 + g * 8);
    const float sqr = sq[nb + row];

    u32 lst[8];
#pragma unroll
    for (int q = 0; q < 8; ++q) lst[q] = 0xFFFFFFFFu;

    const int c0 = w * 1024;
    const size_t cb = (nb + c0 + lc) * CF + (size_t)g * 8;

    bf16x8 slot[4][2];
#pragma unroll
    for (int j = 0; j < 4; ++j) {
        slot[j][0] = *(const bf16x8*)(ybf + cb + (size_t)j * 16 * CF);
        slot[j][1] = *(const bf16x8*)(ybf + cb + (size_t)j * 16 * CF + 32);
    }

    __syncthreads();   // sqlds ready

    const f32x4 zro = {0.f, 0.f, 0.f, 0.f};

#define CONSUME(J, CT, REFILL)                                                  \
    {                                                                           \
        bf16x8 a0 = slot[J][0], a1 = slot[J][1];                                \
        if (REFILL) {                                                           \
            slot[J][0] = *(const bf16x8*)(ybf + cb + (size_t)((CT) + 4) * 16 * CF);      \
            slot[J][1] = *(const bf16x8*)(ybf + cb + (size_t)((CT) + 4) * 16 * CF + 32); \
        }                                                                       \
        f32x4 sc = *(const f32x4*)&sqlds[c0 + (CT) * 16 + g * 4];               \
        f32x4 acc = __builtin_amdgcn_mfma_f32_16x16x32_bf16(a0, rf0, zro, 0, 0, 0); \
        acc = __builtin_amdgcn_mfma_f32_16x16x32_bf16(a1, rf1, acc, 0, 0, 0);   \
        _Pragma("unroll")                                                       \
        for (int r = 0; r < 4; ++r) {                                           \
            float d2a = fmaxf((sqr + sc[r]) - 2.f * acc[r], 0.f);               \
            u32 key = (__float_as_uint(d2a) & 0xFFFFFF00u) | (u32)((CT) * 4 + r); \
            insert8_med3(lst, key);                                             \
        }                                                                       \
    }

    for (int g16 = 0; g16 < 15; ++g16) {
        const int ct0 = g16 * 4;
        CONSUME(0, ct0 + 0, 1)
        CONSUME(1, ct0 + 1, 1)
        CONSUME(2, ct0 + 2, 1)
        CONSUME(3, ct0 + 3, 1)
    }
    CONSUME(0, 60, 0)
    CONSUME(1, 61, 0)
    CONSUME(2, 62, 0)
    CONSUME(3, 63, 0)
#undef CONSUME

#pragma unroll
    for (int q = 0; q < 8; ++q)
        mlds[lc * 129 + (w * 4 + g) * 8 + q] = lst[q];
    __syncthreads();

    if (tid < 64) {
        const int mrow = tid >> 2, s4 = tid & 3;
        u64 top8[8];
#pragma unroll
        for (int q = 0; q < 8; ++q) top8[q] = ~0ull;
#pragma unroll
        for (int s = 0; s < 4; ++s) {
            const int src = s4 * 4 + s;
            const u32 colhi = (src >> 2) * 1024 + (src & 3) * 4;
#pragma unroll
            for (int q = 0; q < 8; ++q) {
                u32 k = mlds[mrow * 129 + src * 8 + q];
                u32 idx8 = k & 0xFFu;
                u32 col = colhi + (idx8 >> 2) * 16 + (idx8 & 3);
                u64 mk = ((u64)(k & 0xFFFFFF00u) << 24) | col;
                if (mk < top8[7]) insertM64<8>(top8, mk);
            }
        }
#pragma unroll
        for (int q = 0; q < 8; ++q)
            cidx[mrow][s4 * 8 + q] = (u32)(top8[q] & 0xFFFu);
    }
    __syncthreads();

    {
        const int rrow = tid >> 4, s = tid & 15;
        const float4* yr = (const float4*)(yf + (nb + r0 + rrow) * CF);
        const float sr = sqlds[r0 + rrow];
#pragma unroll
        for (int j2 = 0; j2 < 2; ++j2) {
            const int q = s * 2 + j2;
            const u32 col = cidx[rrow][q];
            const float4* yc = (const float4*)(yf + (nb + col) * CF);
            float a = 0.f;
#pragma unroll
            for (int k = 0; k < 16; ++k) {
                float4 av = yr[k], bv = yc[k];
                a += av.x * bv.x;
                a += av.y * bv.y;
                a += av.z * bv.z;
                a += av.w * bv.w;
            }
            float d2 = (sr + sqlds[col]) - 2.0f * a;
            float dd = sqrtf(fmaxf(d2, 0.0f));
            ckey[rrow][q] = ((u64)__float_as_uint(dd) << 32) | col;
        }
    }
    __syncthreads();

    if (tid < 16) {
        u64 t7[KNN];
#pragma unroll
        for (int q = 0; q < KNN; ++q) t7[q] = ~0ull;
#pragma unroll
        for (int q = 0; q < 32; ++q) {
            u64 k = ckey[tid][q];
            if (k < t7[KNN - 1]) insertM64<KNN>(t7, k);
        }
#pragma unroll
        for (int q = 0; q < KNN; ++q)
            cidx[tid][q] = (u32)(t7[q] & 0xFFFFFFFFu);
    }
    __syncthreads();

    if (tid < 16 * KNN) {
        const int orow = tid / KNN, q = tid % KNN;
        u32 col = cidx[orow][q];
        adj[(nb + r0 + orow) * NN + col] = 1.0f;
    }
}

// ------------------------------------------------ launcher
// MEASUREMENT ROUND: screen launched 3x (idempotent). T = convZ + 3*screen;
// with R14's convZ + screen = 138.6 -> screen = (T - 138.6)/2.
extern "C" void kernel_launch(void* const* d_in, const int* in_sizes, int n_in,
                              void* d_out, int out_size, void* d_ws, size_t ws_size,
                              hipStream_t stream) {
    const float* x = (const float*)d_in[0];
    const float* w = (const float*)d_in[1];
    const float* bias = (const float*)d_in[2];

    float* y = (float*)d_out;                               // [4][4096][64]
    float* adj = (float*)d_out + (size_t)BATCH * NN * CF;   // [4][4096][4096]

    float* sq = (float*)d_ws;                               // 64 KB
    u16* ybf = (u16*)((char*)d_ws + 65536);                 // 2 MB bf16 features

    conv_fused_kernel<<<4096, 256, 0, stream>>>(x, w, bias, y, ybf, sq,
                                                (float4*)adj);
    screen_kernel<<<1024, 256, 0, stream>>>(ybf, y, sq, adj);
    screen_kernel<<<1024, 256, 0, stream>>>(ybf, y, sq, adj);
    screen_kernel<<<1024, 256, 0, stream>>>(ybf, y, sq, adj);
}

// Round 17
// 108.001 us; speedup vs baseline: 2.9758x; 2.9758x over previous
//
#include <hip/hip_runtime.h>
#include <stdint.h>

#define BATCH 4
#define CINCH 3
#define HIN 128
#define WIN 128
#define NN 4096      // 64*64 output nodes per batch
#define CF 64        // feature channels
#define KNN 7

typedef unsigned short u16;
typedef unsigned u32;
typedef unsigned long long u64;
typedef __attribute__((ext_vector_type(8))) short bf16x8;
typedef __attribute__((ext_vector_type(4))) float f32x4;

// ---------------------------------------------------------------- helpers
__device__ __forceinline__ u64 u64min(u64 a, u64 b) { return a < b ? a : b; }
__device__ __forceinline__ u32 u32min(u32 a, u32 b) { return a < b ? a : b; }

__device__ __forceinline__ u32 med3_u32(u32 a, u32 b, u32 c) {
    u32 d;
    asm("v_med3_u32 %0, %1, %2, %3" : "=v"(d) : "v"(a), "v"(b), "v"(c));
    return d;
}

// branchless sorted top-8 insert (ascending)
__device__ __forceinline__ void insert8_med3(u32* l, u32 k) {
    l[7] = med3_u32(l[6], l[7], k);
    l[6] = med3_u32(l[5], l[6], k);
    l[5] = med3_u32(l[4], l[5], k);
    l[4] = med3_u32(l[3], l[4], k);
    l[3] = med3_u32(l[2], l[3], k);
    l[2] = med3_u32(l[1], l[2], k);
    l[1] = med3_u32(l[0], l[1], k);
    l[0] = u32min(l[0], k);
}

template <int M>
__device__ __forceinline__ void insertM64(u64* lst, u64 k) {
    u64 cur = k;
#pragma unroll
    for (int i = 0; i < M; ++i) {
        u64 lo = u64min(lst[i], cur);
        u64 hi = (lst[i] < cur) ? cur : lst[i];
        lst[i] = lo;
        cur = hi;
    }
}

// ------------------------------------------------ K1: conv + sq + quant + adj zeros
// Same as R14 except ybf is written in MFMA-tile-major layout:
// ybf2[((b*256 + (n>>4))*8 + (c>>3))*128 + (n&15)*8 + (c&7)]
__global__ __launch_bounds__(256) void conv_fused_kernel(
    const float* __restrict__ x, const float* __restrict__ w,
    const float* __restrict__ bias, float* __restrict__ y,
    u16* __restrict__ ybf, float* __restrict__ sq, float4* __restrict__ adj4) {
    __shared__ float ws[CF * CINCH * 9];
    __shared__ float bs[CF];
    for (int i = threadIdx.x; i < CF * CINCH * 9; i += 256) ws[i] = w[i];
    if (threadIdx.x < CF) bs[threadIdx.x] = bias[threadIdx.x];

    {
        float4* dst = adj4 + (size_t)blockIdx.x * 4096;
        const float4 z = make_float4(0.f, 0.f, 0.f, 0.f);
#pragma unroll
        for (int k = 0; k < 16; ++k) dst[k * 256 + threadIdx.x] = z;
    }
    __syncthreads();

    int gid = blockIdx.x * 256 + threadIdx.x;   // ((b*4096)+n)*64 + c
    int c = gid & 63;                            // == lane
    int n = (gid >> 6) & (NN - 1);
    int b = gid >> 18;
    int oh = n >> 6, ow = n & 63;
    const float* xb = x + (size_t)b * CINCH * HIN * WIN;
    float acc = bs[c];
#pragma unroll
    for (int cin = 0; cin < CINCH; ++cin) {
#pragma unroll
        for (int kh = 0; kh < 3; ++kh) {
            int ih = oh * 2 - 1 + kh;
            if (ih < 0 || ih >= HIN) continue;
#pragma unroll
            for (int kw = 0; kw < 3; ++kw) {
                int iw = ow * 2 - 1 + kw;
                if (iw < 0 || iw >= WIN) continue;
                acc += xb[(cin * HIN + ih) * WIN + iw] *
                       ws[(c * CINCH + cin) * 9 + kh * 3 + kw];
            }
        }
    }
    y[(size_t)gid] = acc;

    // bf16 RNE quant -> tile-major layout
    uint32_t u = __float_as_uint(acc);
    u16 hv = (u16)((u + 0x7fffu + ((u >> 16) & 1u)) >> 16);
    size_t ti = ((size_t)(b * 256 + (n >> 4)) * 8 + (c >> 3)) * 128 +
                (size_t)(n & 15) * 8 + (c & 7);
    ybf[ti] = hv;

    float s = acc * acc;
#pragma unroll
    for (int off = 32; off; off >>= 1) s += __shfl_xor(s, off, 64);
    if (c == 0) sq[gid >> 6] = s;
}

// ------------------------------------------------ K2: screen + rescore + ones
// R14 structure; fragment loads are now CONTIGUOUS 1-KB wave accesses thanks to
// the tile-major ybf layout (lane l reads bytes l*16..l*16+15 of each tile).
// Bitwise-identical per-lane data => identical selection output.
__global__ __launch_bounds__(256, 4) void screen_kernel(
    const u16* __restrict__ ybf, const float* __restrict__ yf,
    const float* __restrict__ sq, float* __restrict__ adj) {
    __shared__ float sqlds[NN];          // 16 KB
    __shared__ u32 mlds[16 * 129];       // 8.25 KB
    __shared__ u64 ckey[16][32];         // 4 KB
    __shared__ u32 cidx[16][32];         // 2 KB

    const int bid = blockIdx.x;
    const int b = bid >> 8;
    const int r0 = (bid & 255) << 4;     // 16 rows per block
    const int tid = threadIdx.x, w = tid >> 6, lane = tid & 63;
    const int lc = lane & 15, g = lane >> 4;
    const size_t nb = (size_t)b * NN;

    {
        const float4* s4 = (const float4*)(sq + nb);
        float4* d4 = (float4*)sqlds;
#pragma unroll
        for (int i = 0; i < 4; ++i) d4[i * 256 + tid] = s4[i * 256 + tid];
    }

    // B-operand: this block's row-tile (tile index r0>>4), contiguous loads
    const size_t rb = ((size_t)(b * 256) + (r0 >> 4)) * 1024 + (size_t)lane * 8;
    bf16x8 rf0 = *(const bf16x8*)(ybf + rb);
    bf16x8 rf1 = *(const bf16x8*)(ybf + rb + 512);
    const float sqr = sq[nb + r0 + lc];

    u32 lst[8];
#pragma unroll
    for (int q = 0; q < 8; ++q) lst[q] = 0xFFFFFFFFu;

    const int c0 = w * 1024;             // this wave's column quarter
    // wave's tile base in tile-major ybf (u16 units): tiles w*64 + ct
    const size_t tb = ((size_t)(b * 256) + (w << 6)) * 1024 + (size_t)lane * 8;

    // prologue: fill 4 slots (tiles 0..3), 8 contiguous loads in flight
    bf16x8 slot[4][2];
#pragma unroll
    for (int j = 0; j < 4; ++j) {
        slot[j][0] = *(const bf16x8*)(ybf + tb + (size_t)j * 1024);
        slot[j][1] = *(const bf16x8*)(ybf + tb + (size_t)j * 1024 + 512);
    }

    __syncthreads();   // sqlds ready

    const f32x4 zro = {0.f, 0.f, 0.f, 0.f};

#define CONSUME(J, CT, REFILL)                                                  \
    {                                                                           \
        bf16x8 a0 = slot[J][0], a1 = slot[J][1];                                \
        if (REFILL) {                                                           \
            slot[J][0] = *(const bf16x8*)(ybf + tb + (size_t)((CT) + 4) * 1024);       \
            slot[J][1] = *(const bf16x8*)(ybf + tb + (size_t)((CT) + 4) * 1024 + 512); \
        }                                                                       \
        f32x4 sc = *(const f32x4*)&sqlds[c0 + (CT) * 16 + g * 4];               \
        f32x4 acc = __builtin_amdgcn_mfma_f32_16x16x32_bf16(a0, rf0, zro, 0, 0, 0); \
        acc = __builtin_amdgcn_mfma_f32_16x16x32_bf16(a1, rf1, acc, 0, 0, 0);   \
        _Pragma("unroll")                                                       \
        for (int r = 0; r < 4; ++r) {                                           \
            float d2a = fmaxf((sqr + sc[r]) - 2.f * acc[r], 0.f);               \
            u32 key = (__float_as_uint(d2a) & 0xFFFFFF00u) | (u32)((CT) * 4 + r); \
            insert8_med3(lst, key);                                             \
        }                                                                       \
    }

    for (int g16 = 0; g16 < 15; ++g16) {
        const int ct0 = g16 * 4;
        CONSUME(0, ct0 + 0, 1)
        CONSUME(1, ct0 + 1, 1)
        CONSUME(2, ct0 + 2, 1)
        CONSUME(3, ct0 + 3, 1)
    }
    CONSUME(0, 60, 0)
    CONSUME(1, 61, 0)
    CONSUME(2, 62, 0)
    CONSUME(3, 63, 0)
#undef CONSUME

    // dump per-lane lists: row = lc, src = w*4+g
#pragma unroll
    for (int q = 0; q < 8; ++q)
        mlds[lc * 129 + (w * 4 + g) * 8 + q] = lst[q];
    __syncthreads();

    // phase M: 4 threads/row, merge 4 sources -> top-8 (trunc-key + col order)
    if (tid < 64) {
        const int mrow = tid >> 2, s4 = tid & 3;
        u64 top8[8];
#pragma unroll
        for (int q = 0; q < 8; ++q) top8[q] = ~0ull;
#pragma unroll
        for (int s = 0; s < 4; ++s) {
            const int src = s4 * 4 + s;
            const u32 colhi = (src >> 2) * 1024 + (src & 3) * 4;
#pragma unroll
            for (int q = 0; q < 8; ++q) {
                u32 k = mlds[mrow * 129 + src * 8 + q];
                u32 idx8 = k & 0xFFu;
                u32 col = colhi + (idx8 >> 2) * 16 + (idx8 & 3);
                u64 mk = ((u64)(k & 0xFFFFFF00u) << 24) | col;
                if (mk < top8[7]) insertM64<8>(top8, mk);
            }
        }
#pragma unroll
        for (int q = 0; q < 8; ++q)
            cidx[mrow][s4 * 8 + q] = (u32)(top8[q] & 0xFFFu);
    }
    __syncthreads();

    // phase R: exact f32 rescore (trusted chain), 16 threads/row x 2 cands
    {
        const int rrow = tid >> 4, s = tid & 15;
        const float4* yr = (const float4*)(yf + (nb + r0 + rrow) * CF);
        const float sr = sqlds[r0 + rrow];
#pragma unroll
        for (int j2 = 0; j2 < 2; ++j2) {
            const int q = s * 2 + j2;
            const u32 col = cidx[rrow][q];
            const float4* yc = (const float4*)(yf + (nb + col) * CF);
            float a = 0.f;
#pragma unroll
            for (int k = 0; k < 16; ++k) {
                float4 av = yr[k], bv = yc[k];
                a += av.x * bv.x;
                a += av.y * bv.y;
                a += av.z * bv.z;
                a += av.w * bv.w;
            }
            float d2 = (sr + sqlds[col]) - 2.0f * a;
            float dd = sqrtf(fmaxf(d2, 0.0f));
            ckey[rrow][q] = ((u64)__float_as_uint(dd) << 32) | col;
        }
    }
    __syncthreads();

    // phase F: exact top-7 of 32 candidates
    if (tid < 16) {
        u64 t7[KNN];
#pragma unroll
        for (int q = 0; q < KNN; ++q) t7[q] = ~0ull;
#pragma unroll
        for (int q = 0; q < 32; ++q) {
            u64 k = ckey[tid][q];
            if (k < t7[KNN - 1]) insertM64<KNN>(t7, k);
        }
#pragma unroll
        for (int q = 0; q < KNN; ++q)
            cidx[tid][q] = (u32)(t7[q] & 0xFFFFFFFFu);
    }
    __syncthreads();

    // phase O: 7 ones per row (zeros pre-laid by conv_fused_kernel)
    if (tid < 16 * KNN) {
        const int orow = tid / KNN, q = tid % KNN;
        u32 col = cidx[orow][q];
        adj[(nb + r0 + orow) * NN + col] = 1.0f;
    }
}

// ------------------------------------------------ launcher
extern "C" void kernel_launch(void* const* d_in, const int* in_sizes, int n_in,
                              void* d_out, int out_size, void* d_ws, size_t ws_size,
                              hipStream_t stream) {
    const float* x = (const float*)d_in[0];
    const float* w = (const float*)d_in[1];
    const float* bias = (const float*)d_in[2];

    float* y = (float*)d_out;                               // [4][4096][64]
    float* adj = (float*)d_out + (size_t)BATCH * NN * CF;   // [4][4096][4096]

    float* sq = (float*)d_ws;                               // 64 KB
    u16* ybf = (u16*)((char*)d_ws + 65536);                 // 2 MB tile-major bf16

    conv_fused_kernel<<<4096, 256, 0, stream>>>(x, w, bias, y, ybf, sq,
                                                (float4*)adj);
    screen_kernel<<<1024, 256, 0, stream>>>(ybf, y, sq, adj);
}

// Round 18
// 95.715 us; speedup vs baseline: 3.3577x; 1.1284x over previous
//
#include <hip/hip_runtime.h>
#include <stdint.h>

#define BATCH 4
#define CINCH 3
#define HIN 128
#define WIN 128
#define NN 4096      // 64*64 output nodes per batch
#define CF 64        // feature channels
#define KNN 7

typedef unsigned short u16;
typedef unsigned u32;
typedef unsigned long long u64;
typedef __attribute__((ext_vector_type(8))) short bf16x8;
typedef __attribute__((ext_vector_type(4))) float f32x4;

// ---------------------------------------------------------------- helpers
__device__ __forceinline__ u64 u64min(u64 a, u64 b) { return a < b ? a : b; }
__device__ __forceinline__ u32 u32min(u32 a, u32 b) { return a < b ? a : b; }

__device__ __forceinline__ u32 med3_u32(u32 a, u32 b, u32 c) {
    u32 d;
    asm("v_med3_u32 %0, %1, %2, %3" : "=v"(d) : "v"(a), "v"(b), "v"(c));
    return d;
}

// branchless sorted top-8 insert (ascending)
__device__ __forceinline__ void insert8_med3(u32* l, u32 k) {
    l[7] = med3_u32(l[6], l[7], k);
    l[6] = med3_u32(l[5], l[6], k);
    l[5] = med3_u32(l[4], l[5], k);
    l[4] = med3_u32(l[3], l[4], k);
    l[3] = med3_u32(l[2], l[3], k);
    l[2] = med3_u32(l[1], l[2], k);
    l[1] = med3_u32(l[0], l[1], k);
    l[0] = u32min(l[0], k);
}

template <int M>
__device__ __forceinline__ void insertM64(u64* lst, u64 k) {
    u64 cur = k;
#pragma unroll
    for (int i = 0; i < M; ++i) {
        u64 lo = u64min(lst[i], cur);
        u64 hi = (lst[i] < cur) ? cur : lst[i];
        lst[i] = lo;
        cur = hi;
    }
}

// ------------------------------------------------ K1: conv + sq + tile-major quant
// One wave = one node (c == lane). acc chain bitwise-identical to prior rounds.
// No adj writes here anymore (zeros moved into screen's idle HBM slots).
__global__ __launch_bounds__(256) void conv_fused_kernel(
    const float* __restrict__ x, const float* __restrict__ w,
    const float* __restrict__ bias, float* __restrict__ y,
    u16* __restrict__ ybf, float* __restrict__ sq) {
    __shared__ float ws[CF * CINCH * 9];
    __shared__ float bs[CF];
    for (int i = threadIdx.x; i < CF * CINCH * 9; i += 256) ws[i] = w[i];
    if (threadIdx.x < CF) bs[threadIdx.x] = bias[threadIdx.x];
    __syncthreads();

    int gid = blockIdx.x * 256 + threadIdx.x;   // ((b*4096)+n)*64 + c
    int c = gid & 63;                            // == lane
    int n = (gid >> 6) & (NN - 1);
    int b = gid >> 18;
    int oh = n >> 6, ow = n & 63;
    const float* xb = x + (size_t)b * CINCH * HIN * WIN;
    float acc = bs[c];
#pragma unroll
    for (int cin = 0; cin < CINCH; ++cin) {
#pragma unroll
        for (int kh = 0; kh < 3; ++kh) {
            int ih = oh * 2 - 1 + kh;
            if (ih < 0 || ih >= HIN) continue;
#pragma unroll
            for (int kw = 0; kw < 3; ++kw) {
                int iw = ow * 2 - 1 + kw;
                if (iw < 0 || iw >= WIN) continue;
                acc += xb[(cin * HIN + ih) * WIN + iw] *
                       ws[(c * CINCH + cin) * 9 + kh * 3 + kw];
            }
        }
    }
    y[(size_t)gid] = acc;

    // bf16 RNE quant -> tile-major layout:
    // ybf[((b*256 + (n>>4))*8 + (c>>3))*128 + (n&15)*8 + (c&7)]
    uint32_t u = __float_as_uint(acc);
    u16 hv = (u16)((u + 0x7fffu + ((u >> 16) & 1u)) >> 16);
    size_t ti = ((size_t)(b * 256 + (n >> 4)) * 8 + (c >> 3)) * 128 +
                (size_t)(n & 15) * 8 + (c & 7);
    ybf[ti] = hv;

    float s = acc * acc;
#pragma unroll
    for (int off = 32; off; off >>= 1) s += __shfl_xor(s, off, 64);
    if (c == 0) sq[gid >> 6] = s;
}

// ------------------------------------------------ K2: screen + zeros + rescore + ones
// 1024 blocks, 256 threads, 4 blocks/CU. R17's contiguous tile-major loads +
// R10's interleaved zero-store (1 f32x4/thread/iter -> block's 16 adj rows,
// draining under the 60 us of select compute). Selection bitwise = R17.
__global__ __launch_bounds__(256, 4) void screen_kernel(
    const u16* __restrict__ ybf, const float* __restrict__ yf,
    const float* __restrict__ sq, float* __restrict__ adj) {
    __shared__ float sqlds[NN];          // 16 KB
    __shared__ u32 mlds[16 * 129];       // 8.25 KB
    __shared__ u64 ckey[16][32];         // 4 KB
    __shared__ u32 cidx[16][32];         // 2 KB

    const int bid = blockIdx.x;
    const int b = bid >> 8;
    const int r0 = (bid & 255) << 4;     // 16 rows per block
    const int tid = threadIdx.x, w = tid >> 6, lane = tid & 63;
    const int lc = lane & 15, g = lane >> 4;
    const size_t nb = (size_t)b * NN;

    {
        const float4* s4 = (const float4*)(sq + nb);
        float4* d4 = (float4*)sqlds;
#pragma unroll
        for (int i = 0; i < 4; ++i) d4[i * 256 + tid] = s4[i * 256 + tid];
    }

    // B-operand: this block's row-tile, contiguous tile-major loads
    const size_t rb = ((size_t)(b * 256) + (r0 >> 4)) * 1024 + (size_t)lane * 8;
    bf16x8 rf0 = *(const bf16x8*)(ybf + rb);
    bf16x8 rf1 = *(const bf16x8*)(ybf + rb + 512);
    const float sqr = sq[nb + r0 + lc];

    u32 lst[8];
#pragma unroll
    for (int q = 0; q < 8; ++q) lst[q] = 0xFFFFFFFFu;

    const int c0 = w * 1024;             // this wave's column quarter
    const size_t tb = ((size_t)(b * 256) + (w << 6)) * 1024 + (size_t)lane * 8;

    // zero-store stream: thread covers row r0+(tid>>4), one f32x4 per iter
    f32x4* zrow = (f32x4*)(adj + (nb + r0 + (tid >> 4)) * NN) + (tid & 15);
    const f32x4 zf4 = {0.f, 0.f, 0.f, 0.f};

    // prologue: fill 4 slots, 8 contiguous loads in flight
    bf16x8 slot[4][2];
#pragma unroll
    for (int j = 0; j < 4; ++j) {
        slot[j][0] = *(const bf16x8*)(ybf + tb + (size_t)j * 1024);
        slot[j][1] = *(const bf16x8*)(ybf + tb + (size_t)j * 1024 + 512);
    }

    __syncthreads();   // sqlds ready

    const f32x4 zro = {0.f, 0.f, 0.f, 0.f};

#define CONSUME(J, CT, REFILL)                                                  \
    {                                                                           \
        bf16x8 a0 = slot[J][0], a1 = slot[J][1];                                \
        if (REFILL) {                                                           \
            slot[J][0] = *(const bf16x8*)(ybf + tb + (size_t)((CT) + 4) * 1024);       \
            slot[J][1] = *(const bf16x8*)(ybf + tb + (size_t)((CT) + 4) * 1024 + 512); \
        }                                                                       \
        zrow[(CT) * 16] = zf4;  /* zero-store rides idle HBM under compute */   \
        f32x4 sc = *(const f32x4*)&sqlds[c0 + (CT) * 16 + g * 4];               \
        f32x4 acc = __builtin_amdgcn_mfma_f32_16x16x32_bf16(a0, rf0, zro, 0, 0, 0); \
        acc = __builtin_amdgcn_mfma_f32_16x16x32_bf16(a1, rf1, acc, 0, 0, 0);   \
        _Pragma("unroll")                                                       \
        for (int r = 0; r < 4; ++r) {                                           \
            float d2a = fmaxf((sqr + sc[r]) - 2.f * acc[r], 0.f);               \
            u32 key = (__float_as_uint(d2a) & 0xFFFFFF00u) | (u32)((CT) * 4 + r); \
            insert8_med3(lst, key);                                             \
        }                                                                       \
    }

    for (int g16 = 0; g16 < 15; ++g16) {
        const int ct0 = g16 * 4;
        CONSUME(0, ct0 + 0, 1)
        CONSUME(1, ct0 + 1, 1)
        CONSUME(2, ct0 + 2, 1)
        CONSUME(3, ct0 + 3, 1)
    }
    CONSUME(0, 60, 0)
    CONSUME(1, 61, 0)
    CONSUME(2, 62, 0)
    CONSUME(3, 63, 0)
#undef CONSUME

    // dump per-lane lists: row = lc, src = w*4+g
#pragma unroll
    for (int q = 0; q < 8; ++q)
        mlds[lc * 129 + (w * 4 + g) * 8 + q] = lst[q];
    __syncthreads();

    // phase M: 4 threads/row, merge 4 sources -> top-8 (trunc-key + col order)
    if (tid < 64) {
        const int mrow = tid >> 2, s4 = tid & 3;
        u64 top8[8];
#pragma unroll
        for (int q = 0; q < 8; ++q) top8[q] = ~0ull;
#pragma unroll
        for (int s = 0; s < 4; ++s) {
            const int src = s4 * 4 + s;
            const u32 colhi = (src >> 2) * 1024 + (src & 3) * 4;
#pragma unroll
            for (int q = 0; q < 8; ++q) {
                u32 k = mlds[mrow * 129 + src * 8 + q];
                u32 idx8 = k & 0xFFu;
                u32 col = colhi + (idx8 >> 2) * 16 + (idx8 & 3);
                u64 mk = ((u64)(k & 0xFFFFFF00u) << 24) | col;
                if (mk < top8[7]) insertM64<8>(top8, mk);
            }
        }
#pragma unroll
        for (int q = 0; q < 8; ++q)
            cidx[mrow][s4 * 8 + q] = (u32)(top8[q] & 0xFFFu);
    }
    __syncthreads();

    // phase R: exact f32 rescore (trusted chain), 16 threads/row x 2 cands
    {
        const int rrow = tid >> 4, s = tid & 15;
        const float4* yr = (const float4*)(yf + (nb + r0 + rrow) * CF);
        const float sr = sqlds[r0 + rrow];
#pragma unroll
        for (int j2 = 0; j2 < 2; ++j2) {
            const int q = s * 2 + j2;
            const u32 col = cidx[rrow][q];
            const float4* yc = (const float4*)(yf + (nb + col) * CF);
            float a = 0.f;
#pragma unroll
            for (int k = 0; k < 16; ++k) {
                float4 av = yr[k], bv = yc[k];
                a += av.x * bv.x;
                a += av.y * bv.y;
                a += av.z * bv.z;
                a += av.w * bv.w;
            }
            float d2 = (sr + sqlds[col]) - 2.0f * a;
            float dd = sqrtf(fmaxf(d2, 0.0f));
            ckey[rrow][q] = ((u64)__float_as_uint(dd) << 32) | col;
        }
    }
    __syncthreads();

    // phase F: exact top-7 of 32 candidates
    if (tid < 16) {
        u64 t7[KNN];
#pragma unroll
        for (int q = 0; q < KNN; ++q) t7[q] = ~0ull;
#pragma unroll
        for (int q = 0; q < 32; ++q) {
            u64 k = ckey[tid][q];
            if (k < t7[KNN - 1]) insertM64<KNN>(t7, k);
        }
#pragma unroll
        for (int q = 0; q < KNN; ++q)
            cidx[tid][q] = (u32)(t7[q] & 0xFFFFFFFFu);
    }
    __syncthreads();

    // phase O: 7 ones per row (this block's zeros drained at the barriers)
    if (tid < 16 * KNN) {
        const int orow = tid / KNN, q = tid % KNN;
        u32 col = cidx[orow][q];
        adj[(nb + r0 + orow) * NN + col] = 1.0f;
    }
}

// ------------------------------------------------ launcher
extern "C" void kernel_launch(void* const* d_in, const int* in_sizes, int n_in,
                              void* d_out, int out_size, void* d_ws, size_t ws_size,
                              hipStream_t stream) {
    const float* x = (const float*)d_in[0];
    const float* w = (const float*)d_in[1];
    const float* bias = (const float*)d_in[2];

    float* y = (float*)d_out;                               // [4][4096][64]
    float* adj = (float*)d_out + (size_t)BATCH * NN * CF;   // [4][4096][4096]

    float* sq = (float*)d_ws;                               // 64 KB
    u16* ybf = (u16*)((char*)d_ws + 65536);                 // 2 MB tile-major bf16

    conv_fused_kernel<<<4096, 256, 0, stream>>>(x, w, bias, y, ybf, sq);
    screen_kernel<<<1024, 256, 0, stream>>>(ybf, y, sq, adj);
}